// Round 12
// baseline (921.203 us; speedup 1.0000x reference)
//
#include <hip/hip_runtime.h>
#include <hip/hip_bf16.h>
#include <hip/hip_cooperative_groups.h>

namespace cg = cooperative_groups;

#define NNODES 25000
#define NEDGES 400000
#define DIM 128
#define NGRAPHS 512
#define DOUT 10
#define NPAD 32768
#define NCOPY 8
#define MTILES ((NNODES + 31) / 32)   // 782

typedef short bf16x8 __attribute__((ext_vector_type(8)));
typedef float f32x4 __attribute__((ext_vector_type(4)));

__device__ inline float bfu_lo(unsigned int u) {
  union { unsigned int i; float f; } v; v.i = u << 16; return v.f;
}
__device__ inline float bfu_hi(unsigned int u) {
  union { unsigned int i; float f; } v; v.i = u & 0xffff0000u; return v.f;
}
__device__ inline unsigned short f2bf(float f) {
  union { float f; unsigned int i; } v; v.f = f;
  unsigned int r = v.i + 0x7fff + ((v.i >> 16) & 1);
  return (unsigned short)(r >> 16);
}

__device__ inline int lower_bound_i(const int* a, int n, int key) {
  int lo = 0, hi = n;
  while (lo < hi) {
    int m = (lo + hi) >> 1;
    if (a[m] < key) lo = m + 1; else hi = m;
  }
  return lo;
}

__global__ __launch_bounds__(256, 4) void k_mega(
    const int* __restrict__ src, const int* __restrict__ dst,
    const float* __restrict__ x, const int* __restrict__ batch,
    const float* __restrict__ W1, const float* __restrict__ b1,
    const float* __restrict__ gamma, const float* __restrict__ beta,
    const float* __restrict__ rmean, const float* __restrict__ rvar,
    const float* __restrict__ W2, const float* __restrict__ b2,
    const float* __restrict__ epsv, const float* __restrict__ Wout,
    const float* __restrict__ bout, float* __restrict__ out,
    int* __restrict__ deg8, int* __restrict__ cursor8, int* __restrict__ offs,
    int* __restrict__ csr, int* __restrict__ blocksum,
    unsigned short* __restrict__ h0, unsigned short* __restrict__ aggbuf,
    unsigned short* __restrict__ hA, unsigned short* __restrict__ hB,
    unsigned short* __restrict__ W1T, unsigned short* __restrict__ W2T) {
  cg::grid_group grid = cg::this_grid();
  __shared__ __align__(16) char smem[8192];
  const int t = threadIdx.x;
  const int blk = blockIdx.x;
  const int nb = gridDim.x;
  const int gtid = blk * 256 + t;
  const int stride = nb * 256;

  // ---------- P0: zero deg8 ----------
  for (int i = gtid; i < NCOPY * NPAD; i += stride) deg8[i] = 0;
  grid.sync();

  // ---------- P1: deg8 histogram + x->bf16 + weight transpose ----------
  {
    int* dp = deg8 + (size_t)(blk & (NCOPY - 1)) * NPAD;
    for (int i = gtid; i < NEDGES; i += stride) atomicAdd(&dp[dst[i]], 1);
    const float4* x4 = (const float4*)x;
    for (int i = gtid; i < NNODES * DIM / 8; i += stride) {
      float4 a = x4[i * 2], c = x4[i * 2 + 1];
      uint4 p;
      p.x = ((unsigned int)f2bf(a.y) << 16) | f2bf(a.x);
      p.y = ((unsigned int)f2bf(a.w) << 16) | f2bf(a.z);
      p.z = ((unsigned int)f2bf(c.y) << 16) | f2bf(c.x);
      p.w = ((unsigned int)f2bf(c.w) << 16) | f2bf(c.z);
      ((uint4*)h0)[i] = p;
    }
    for (int i = gtid; i < 6 * DIM * DIM; i += stride) {
      int m = i >> 14, idx = i & 16383;
      int l = m >> 1;
      const float* win = ((m & 1) ? W2 : W1) + (size_t)l * DIM * DIM;
      unsigned short* wout = ((m & 1) ? W2T : W1T) + (size_t)l * DIM * DIM;
      int cc = idx >> 7, kk = idx & 127;
      wout[idx] = f2bf(win[kk * DIM + cc]);
    }
  }
  grid.sync();

  // ---------- P2a: block-local inclusive scan (32 blocks x 1024 nodes) ----------
  int* ismem = (int*)smem;
  if (blk < 32) {
    int n0 = blk * 1024 + t * 4;
    int4 tot = make_int4(0, 0, 0, 0);
#pragma unroll
    for (int c = 0; c < NCOPY; ++c) {
      int4 v = *(const int4*)(deg8 + (size_t)c * NPAD + n0);
      tot.x += v.x; tot.y += v.y; tot.z += v.z; tot.w += v.w;
    }
    int ts = tot.x + tot.y + tot.z + tot.w;
    ismem[t] = ts;
    __syncthreads();
    for (int off = 1; off < 256; off <<= 1) {
      int u = (t >= off) ? ismem[t - off] : 0;
      __syncthreads();
      ismem[t] += u;
      __syncthreads();
    }
    int excl = ismem[t] - ts;
    int4 o;
    o.x = excl; o.y = o.x + tot.x; o.z = o.y + tot.y; o.w = o.z + tot.z;
    *(int4*)(offs + n0) = o;
    if (t == 255) blocksum[blk] = ismem[255];
  }
  grid.sync();

  // ---------- P2b: add block bases; seed per-copy cursors ----------
  if (blk < 32) {
    int bb = 0;
    for (int b2i = 0; b2i < blk; ++b2i) bb += blocksum[b2i];
    int n0 = blk * 1024 + t * 4;
    int4 lo4 = *(const int4*)(offs + n0);
    lo4.x += bb; lo4.y += bb; lo4.z += bb; lo4.w += bb;
    *(int4*)(offs + n0) = lo4;
    int c0 = lo4.x, c1 = lo4.y, c2 = lo4.z, c3 = lo4.w;
#pragma unroll
    for (int c = 0; c < NCOPY; ++c) {
      int4 v = *(const int4*)(deg8 + (size_t)c * NPAD + n0);
      int* cur = cursor8 + (size_t)c * NPAD + n0;
      cur[0] = c0; c0 += v.x;
      cur[1] = c1; c1 += v.y;
      cur[2] = c2; c2 += v.z;
      cur[3] = c3; c3 += v.w;
    }
  }
  grid.sync();

  // ---------- P3: scatter (same edge->copy mapping as P1) ----------
  {
    int* cur = cursor8 + (size_t)(blk & (NCOPY - 1)) * NPAD;
    for (int i = gtid; i < NEDGES; i += stride) {
      int p = atomicAdd(&cur[dst[i]], 1);
      csr[p] = src[i];
    }
  }
  grid.sync();

  // ---------- layers ----------
  const int lane = t & 63;
  const int wv = t >> 6;
  const int cl = lane & 15;
  const int kg = lane >> 4;
  const unsigned laneB = (unsigned)lane * 4u;
  const unsigned short* hin = h0;

  for (int l = 0; l < 3; ++l) {
    // ---- agg: one wave per node, scalarized CSR ----
    {
      const char* hb = (const char*)hin;
      float eps1 = 1.0f + epsv[l];
      for (int node = blk * 4 + wv; node < NNODES; node += nb * 4) {
        int s = __builtin_amdgcn_readfirstlane(offs[node]);
        int e = __builtin_amdgcn_readfirstlane(offs[node + 1]);
        unsigned int hv = *(const unsigned int*)(hb + (((unsigned)node << 8) + laneB));
        float a0 = eps1 * bfu_lo(hv), a1 = eps1 * bfu_hi(hv);
        float p0 = 0.f, p1 = 0.f, q0 = 0.f, q1 = 0.f;
        float r0f = 0.f, r1f = 0.f, u0 = 0.f, u1 = 0.f;
        int j = s;
        for (; j + 7 < e; j += 8) {
          unsigned o0 = (unsigned)__builtin_amdgcn_readfirstlane(csr[j + 0]) << 8;
          unsigned o1 = (unsigned)__builtin_amdgcn_readfirstlane(csr[j + 1]) << 8;
          unsigned o2 = (unsigned)__builtin_amdgcn_readfirstlane(csr[j + 2]) << 8;
          unsigned o3 = (unsigned)__builtin_amdgcn_readfirstlane(csr[j + 3]) << 8;
          unsigned o4 = (unsigned)__builtin_amdgcn_readfirstlane(csr[j + 4]) << 8;
          unsigned o5 = (unsigned)__builtin_amdgcn_readfirstlane(csr[j + 5]) << 8;
          unsigned o6 = (unsigned)__builtin_amdgcn_readfirstlane(csr[j + 6]) << 8;
          unsigned o7 = (unsigned)__builtin_amdgcn_readfirstlane(csr[j + 7]) << 8;
          unsigned int v0 = *(const unsigned int*)(hb + (o0 + laneB));
          unsigned int v1 = *(const unsigned int*)(hb + (o1 + laneB));
          unsigned int v2 = *(const unsigned int*)(hb + (o2 + laneB));
          unsigned int v3 = *(const unsigned int*)(hb + (o3 + laneB));
          unsigned int v4 = *(const unsigned int*)(hb + (o4 + laneB));
          unsigned int v5 = *(const unsigned int*)(hb + (o5 + laneB));
          unsigned int v6 = *(const unsigned int*)(hb + (o6 + laneB));
          unsigned int v7 = *(const unsigned int*)(hb + (o7 + laneB));
          a0 += bfu_lo(v0); a1 += bfu_hi(v0);
          p0 += bfu_lo(v1); p1 += bfu_hi(v1);
          q0 += bfu_lo(v2); q1 += bfu_hi(v2);
          r0f += bfu_lo(v3); r1f += bfu_hi(v3);
          u0 += bfu_lo(v4); u1 += bfu_hi(v4);
          a0 += bfu_lo(v5); a1 += bfu_hi(v5);
          p0 += bfu_lo(v6); p1 += bfu_hi(v6);
          q0 += bfu_lo(v7); q1 += bfu_hi(v7);
        }
        for (; j < e; ++j) {
          unsigned o = (unsigned)__builtin_amdgcn_readfirstlane(csr[j]) << 8;
          unsigned int v = *(const unsigned int*)(hb + (o + laneB));
          a0 += bfu_lo(v); a1 += bfu_hi(v);
        }
        a0 += p0 + q0 + r0f + u0;
        a1 += p1 + q1 + r1f + u1;
        ((unsigned int*)aggbuf)[((unsigned)node << 6) + lane] =
            ((unsigned int)f2bf(a1) << 16) | f2bf(a0);
      }
    }
    grid.sync();

    // ---- mlp (MFMA) ----
    {
      const unsigned short* lW1T = W1T + (size_t)l * DIM * DIM;
      const unsigned short* lW2T = W2T + (size_t)l * DIM * DIM;
      const float* lb1 = b1 + l * DIM;
      const float* lg = gamma + l * DIM;
      const float* lbe = beta + l * DIM;
      const float* lrm = rmean + l * DIM;
      const float* lrv = rvar + l * DIM;
      const float* lb2 = b2 + l * DIM;
      unsigned short* hout = (l == 1) ? hB : hA;

      bf16x8 b1f[2][4], b2f[2][4];
      float s1c[2], o1c[2], b2c[2];
#pragma unroll
      for (int ct = 0; ct < 2; ++ct) {
        int col = wv * 32 + ct * 16 + cl;
        const char* p1 = (const char*)(lW1T + (size_t)col * DIM);
        const char* p2 = (const char*)(lW2T + (size_t)col * DIM);
#pragma unroll
        for (int kk = 0; kk < 4; ++kk) {
          b1f[ct][kk] = *(const bf16x8*)(p1 + kk * 64 + kg * 16);
          b2f[ct][kk] = *(const bf16x8*)(p2 + kk * 64 + kg * 16);
        }
        float sc = lg[col] * rsqrtf(lrv[col] + 1e-5f);
        s1c[ct] = sc;
        o1c[ct] = (lb1[col] - lrm[col]) * sc + lbe[col];
        b2c[ct] = lb2[col];
      }

      for (int tile = blk; tile < MTILES; tile += nb) {
        int r0 = tile * 32;
        {
          const uint4* ag4 = (const uint4*)(aggbuf + (size_t)r0 * DIM);
#pragma unroll
          for (int it = 0; it < 2; ++it) {
            int u = t + it * 256;
            int row = u >> 4, un = u & 15;
            uint4 v = make_uint4(0u, 0u, 0u, 0u);
            if (r0 + row < NNODES) v = ag4[u];
            *(uint4*)(smem + row * 256 + ((un * 16) ^ ((row & 7) << 4))) = v;
          }
        }
        __syncthreads();

        f32x4 zero = {0.f, 0.f, 0.f, 0.f};
        f32x4 acc[2][2] = {{zero, zero}, {zero, zero}};
#pragma unroll
        for (int kk = 0; kk < 4; ++kk) {
#pragma unroll
          for (int rt = 0; rt < 2; ++rt) {
            int row = rt * 16 + cl;
            int un = kk * 4 + kg;
            bf16x8 a = *(const bf16x8*)(smem + row * 256 + ((un * 16) ^ ((row & 7) << 4)));
            acc[rt][0] = __builtin_amdgcn_mfma_f32_16x16x32_bf16(a, b1f[0][kk], acc[rt][0], 0, 0, 0);
            acc[rt][1] = __builtin_amdgcn_mfma_f32_16x16x32_bf16(a, b1f[1][kk], acc[rt][1], 0, 0, 0);
          }
        }
        __syncthreads();

#pragma unroll
        for (int rt = 0; rt < 2; ++rt)
#pragma unroll
          for (int ct = 0; ct < 2; ++ct) {
            int col = wv * 32 + ct * 16 + cl;
#pragma unroll
            for (int j = 0; j < 4; ++j) {
              int row = rt * 16 + kg * 4 + j;
              float z = fmaxf(acc[rt][ct][j] * s1c[ct] + o1c[ct], 0.f);
              *(unsigned short*)(smem + row * 256 + ((col * 2) ^ ((row & 7) << 4))) = f2bf(z);
            }
          }
        __syncthreads();

        f32x4 acc2[2][2] = {{zero, zero}, {zero, zero}};
#pragma unroll
        for (int kk = 0; kk < 4; ++kk) {
#pragma unroll
          for (int rt = 0; rt < 2; ++rt) {
            int row = rt * 16 + cl;
            int un = kk * 4 + kg;
            bf16x8 a = *(const bf16x8*)(smem + row * 256 + ((un * 16) ^ ((row & 7) << 4)));
            acc2[rt][0] = __builtin_amdgcn_mfma_f32_16x16x32_bf16(a, b2f[0][kk], acc2[rt][0], 0, 0, 0);
            acc2[rt][1] = __builtin_amdgcn_mfma_f32_16x16x32_bf16(a, b2f[1][kk], acc2[rt][1], 0, 0, 0);
          }
        }
        __syncthreads();

#pragma unroll
        for (int rt = 0; rt < 2; ++rt)
#pragma unroll
          for (int ct = 0; ct < 2; ++ct) {
            int col = wv * 32 + ct * 16 + cl;
#pragma unroll
            for (int j = 0; j < 4; ++j) {
              int row = rt * 16 + kg * 4 + j;
              float hv = fmaxf(acc2[rt][ct][j] + b2c[ct], 0.f);
              *(unsigned short*)(smem + row * 256 + ((col * 2) ^ ((row & 7) << 4))) = f2bf(hv);
            }
          }
        __syncthreads();

        {
          uint4* ho4 = (uint4*)(hout + (size_t)r0 * DIM);
#pragma unroll
          for (int it = 0; it < 2; ++it) {
            int u = t + it * 256;
            int row = u >> 4, un = u & 15;
            if (r0 + row < NNODES) {
              uint4 v = *(const uint4*)(smem + row * 256 + ((un * 16) ^ ((row & 7) << 4)));
              ho4[u] = v;
            }
          }
        }
        __syncthreads();
      }
    }
    grid.sync();
    hin = (l == 1) ? hB : hA;
  }

  // ---------- pool + readout ----------
  {
    float* red = (float*)smem;            // [8][128]
    float* pooled = (float*)(smem + 4096);
    const uint2* h2 = (const uint2*)hin;
    int cg2 = t & 31;
    int st = t >> 5;
    for (int g = blk; g < NGRAPHS; g += nb) {
      int lo = lower_bound_i(batch, NNODES, g);
      int hi = lower_bound_i(batch, NNODES, g + 1);
      float a0 = 0.f, a1 = 0.f, a2 = 0.f, a3 = 0.f;
      for (int i = lo + st; i < hi; i += 8) {
        uint2 v = h2[(size_t)i * 32 + cg2];
        a0 += bfu_lo(v.x); a1 += bfu_hi(v.x); a2 += bfu_lo(v.y); a3 += bfu_hi(v.y);
      }
      red[st * DIM + cg2 * 4 + 0] = a0;
      red[st * DIM + cg2 * 4 + 1] = a1;
      red[st * DIM + cg2 * 4 + 2] = a2;
      red[st * DIM + cg2 * 4 + 3] = a3;
      __syncthreads();
      if (t < DIM) {
        float s = 0.f;
#pragma unroll
        for (int k = 0; k < 8; ++k) s += red[k * DIM + t];
        float cnt = (hi > lo) ? (float)(hi - lo) : 1.0f;
        pooled[t] = s / cnt;
      }
      __syncthreads();
      if (t < DOUT) {
        float acc = bout[t];
#pragma unroll 8
        for (int k = 0; k < DIM; ++k) acc = fmaf(pooled[k], Wout[k * DOUT + t], acc);
        out[g * DOUT + t] = acc;
      }
      __syncthreads();
    }
  }
}

// ---------------- launch ----------------

extern "C" void kernel_launch(void* const* d_in, const int* in_sizes, int n_in,
                              void* d_out, int out_size, void* d_ws, size_t ws_size,
                              hipStream_t stream) {
  const int* src     = (const int*)d_in[1];
  const int* dst     = ((const int*)d_in[1]) + NEDGES;
  const float* x     = (const float*)d_in[0];
  const int* batch   = (const int*)d_in[2];
  const float* W1    = (const float*)d_in[3];
  const float* b1    = (const float*)d_in[4];
  const float* gamma = (const float*)d_in[5];
  const float* beta  = (const float*)d_in[6];
  const float* rmean = (const float*)d_in[7];
  const float* rvar  = (const float*)d_in[8];
  const float* W2    = (const float*)d_in[9];
  const float* b2    = (const float*)d_in[10];
  const float* epsv  = (const float*)d_in[11];
  const float* Wout  = (const float*)d_in[12];
  const float* bout  = (const float*)d_in[13];
  float* out = (float*)d_out;

  char* ws = (char*)d_ws;
  size_t o = 0;
  auto alloc = [&](size_t bytes) -> void* {
    o = (o + 255) & ~(size_t)255;
    void* p = ws + o;
    o += bytes;
    return p;
  };
  int* deg8     = (int*)alloc((size_t)NCOPY * NPAD * sizeof(int));
  int* cursor8  = (int*)alloc((size_t)NCOPY * NPAD * sizeof(int));
  int* offs     = (int*)alloc((NPAD + 8) * sizeof(int));
  int* csr      = (int*)alloc(NEDGES * sizeof(int));
  int* blocksum = (int*)alloc(64 * sizeof(int));
  unsigned short* h0     = (unsigned short*)alloc((size_t)NNODES * DIM * 2);
  unsigned short* aggbuf = (unsigned short*)alloc((size_t)NNODES * DIM * 2);
  unsigned short* hA     = (unsigned short*)alloc((size_t)NNODES * DIM * 2);
  unsigned short* hB     = (unsigned short*)alloc((size_t)NNODES * DIM * 2);
  unsigned short* W1T    = (unsigned short*)alloc(3 * DIM * DIM * 2);
  unsigned short* W2T    = (unsigned short*)alloc(3 * DIM * DIM * 2);

  int maxb = 0;
  hipError_t qerr =
      hipOccupancyMaxActiveBlocksPerMultiprocessor(&maxb, (const void*)k_mega, 256, 0);
  if (qerr != hipSuccess || maxb < 1) maxb = 4;   // defensive fallback
  long long nblk_ll = (long long)maxb * 256;      // 256 CUs on MI355X
  int nblk = (nblk_ll > 2048) ? 2048 : (int)nblk_ll;
  if (nblk < 32) nblk = 32;

  void* args[] = {
      (void*)&src, (void*)&dst, (void*)&x, (void*)&batch,
      (void*)&W1, (void*)&b1, (void*)&gamma, (void*)&beta,
      (void*)&rmean, (void*)&rvar, (void*)&W2, (void*)&b2,
      (void*)&epsv, (void*)&Wout, (void*)&bout, (void*)&out,
      (void*)&deg8, (void*)&cursor8, (void*)&offs, (void*)&csr, (void*)&blocksum,
      (void*)&h0, (void*)&aggbuf, (void*)&hA, (void*)&hB,
      (void*)&W1T, (void*)&W2T};

  hipLaunchCooperativeKernel((const void*)k_mega, dim3(nblk), dim3(256), args, 0,
                             stream);
}

// Round 13
// 248.016 us; speedup vs baseline: 3.7143x; 3.7143x over previous
//
#include <hip/hip_runtime.h>
#include <hip/hip_bf16.h>

#define NNODES 25000
#define NEDGES 400000
#define DIM 128
#define NGRAPHS 512
#define DOUT 10
#define NPAD 32768        // 32 scan blocks * 1024 nodes
#define NCOPY 8           // histogram/cursor replication
#define EDGE_NB 1563      // 1563*256 >= 400000

typedef short bf16x8 __attribute__((ext_vector_type(8)));
typedef float f32x4 __attribute__((ext_vector_type(4)));

__device__ inline float bfu_lo(unsigned int u) {
  union { unsigned int i; float f; } v; v.i = u << 16; return v.f;
}
__device__ inline float bfu_hi(unsigned int u) {
  union { unsigned int i; float f; } v; v.i = u & 0xffff0000u; return v.f;
}
__device__ inline unsigned short f2bf(float f) {
  union { float f; unsigned int i; } v; v.f = f;
  unsigned int r = v.i + 0x7fff + ((v.i >> 16) & 1);
  return (unsigned short)(r >> 16);
}

// ---------------- prep: replicated histogram + weight transpose ----------------
// blocks [0,1563): hist into copy (b&7); [1563,1569): weight transpose.

__global__ __launch_bounds__(256) void k_prep(const int* __restrict__ dst,
                                              int* __restrict__ deg8,
                                              const float* __restrict__ W1,
                                              const float* __restrict__ W2,
                                              unsigned short* __restrict__ W1T,
                                              unsigned short* __restrict__ W2T) {
  int b = blockIdx.x;
  if (b < EDGE_NB) {
    int i = b * 256 + threadIdx.x;
    int* dp = deg8 + (size_t)(b & (NCOPY - 1)) * NPAD;
    if (i < NEDGES) atomicAdd(&dp[dst[i]], 1);
  } else {
    int wb = b - EDGE_NB;      // 0..5
    int l = wb >> 1;
    const float* in = ((wb & 1) ? W2 : W1) + (size_t)l * DIM * DIM;
    unsigned short* out = ((wb & 1) ? W2T : W1T) + (size_t)l * DIM * DIM;
    for (int idx = threadIdx.x; idx < DIM * DIM; idx += 256) {
      int c = idx >> 7, k = idx & 127;
      out[idx] = f2bf(in[k * DIM + c]);
    }
  }
}

// ---------------- scan: 32 blocks, decoupled lookback, seeds per-copy cursors ----------------

__global__ __launch_bounds__(256) void k_scan(const int* __restrict__ deg8,
                                              int* __restrict__ offs,
                                              int* __restrict__ cursor8,
                                              int* __restrict__ bsum,
                                              int* __restrict__ bflag) {
  __shared__ int sh[256];
  __shared__ int sh_base;
  int blk = blockIdx.x;
  int t = threadIdx.x;
  int n0 = blk * 1024 + t * 4;

  // per-thread totals over 8 copies (4 nodes)
  int4 tot = make_int4(0, 0, 0, 0);
#pragma unroll
  for (int c = 0; c < NCOPY; ++c) {
    int4 v = *(const int4*)(deg8 + (size_t)c * NPAD + n0);
    tot.x += v.x; tot.y += v.y; tot.z += v.z; tot.w += v.w;
  }
  int ts = tot.x + tot.y + tot.z + tot.w;
  sh[t] = ts;
  __syncthreads();
  for (int off = 1; off < 256; off <<= 1) {
    int u = (t >= off) ? sh[t - off] : 0;
    __syncthreads();
    sh[t] += u;
    __syncthreads();
  }
  int texcl = sh[t] - ts;
  int btot = sh[255];

  // publish block sum, then look back over predecessors
  if (t == 0) {
    __hip_atomic_store(&bsum[blk], btot, __ATOMIC_RELAXED, __HIP_MEMORY_SCOPE_AGENT);
    __hip_atomic_store(&bflag[blk], 1, __ATOMIC_RELEASE, __HIP_MEMORY_SCOPE_AGENT);
    int base = 0;
    for (int i = 0; i < blk; ++i) {
      while (__hip_atomic_load(&bflag[i], __ATOMIC_ACQUIRE,
                               __HIP_MEMORY_SCOPE_AGENT) == 0) {}
      base += __hip_atomic_load(&bsum[i], __ATOMIC_RELAXED, __HIP_MEMORY_SCOPE_AGENT);
    }
    sh_base = base;
  }
  __syncthreads();
  int base = sh_base + texcl;

  int4 w;
  w.x = base;
  w.y = base + tot.x;
  w.z = w.y + tot.y;
  w.w = w.z + tot.z;
  *(int4*)(offs + n0) = w;

  int b0 = w.x, b1 = w.y, b2 = w.z, b3 = w.w;
#pragma unroll
  for (int c = 0; c < NCOPY; ++c) {
    int4 v = *(const int4*)(deg8 + (size_t)c * NPAD + n0);
    int* cur = cursor8 + (size_t)c * NPAD + n0;
    cur[0] = b0; b0 += v.x;
    cur[1] = b1; b1 += v.y;
    cur[2] = b2; b2 += v.z;
    cur[3] = b3; b3 += v.w;
  }
}

// ---------------- scatter: replicated cursors (same edge->copy mapping as prep) ----------------

__global__ __launch_bounds__(256) void k_scatter(const int* __restrict__ src,
                                                 const int* __restrict__ dst,
                                                 int* __restrict__ cursor8,
                                                 int* __restrict__ csr) {
  int b = blockIdx.x;
  int i = b * 256 + threadIdx.x;
  int* cur = cursor8 + (size_t)(b & (NCOPY - 1)) * NPAD;
  if (i < NEDGES) {
    int p = atomicAdd(&cur[dst[i]], 1);
    csr[p] = src[i];
  }
}

// ---------------- GIN aggregation: one wave per node, scalarized CSR ----------------
// F32IN: layer 0 reads x as f32 directly (no cvt pass); else bf16 h.

template <bool F32IN>
__global__ __launch_bounds__(256) void k_agg(const void* __restrict__ hin,
                                             const int* __restrict__ offs,
                                             const int* __restrict__ csr,
                                             const float* __restrict__ epsp, int layer,
                                             unsigned short* __restrict__ agg) {
  int lane = threadIdx.x & 63;
  int node = blockIdx.x * 4 + (threadIdx.x >> 6);   // grid*4 == NNODES exactly
  const char* hb = (const char*)hin;
  float eps1 = 1.0f + epsp[layer];
  int s = __builtin_amdgcn_readfirstlane(offs[node]);
  int e = __builtin_amdgcn_readfirstlane(offs[node + 1]);

  float a0, a1;   // feature cols 2*lane, 2*lane+1
  if constexpr (F32IN) {
    float2 hv = *(const float2*)(hb + (((unsigned)node << 9) + (unsigned)lane * 8u));
    a0 = eps1 * hv.x; a1 = eps1 * hv.y;
  } else {
    unsigned int hv = *(const unsigned int*)(hb + (((unsigned)node << 8) + (unsigned)lane * 4u));
    a0 = eps1 * bfu_lo(hv); a1 = eps1 * bfu_hi(hv);
  }
  float b0 = 0.f, b1 = 0.f, c0 = 0.f, c1 = 0.f, d0 = 0.f, d1 = 0.f, g0 = 0.f, g1 = 0.f;

  int j = s;
  if constexpr (F32IN) {
    unsigned laneB = (unsigned)lane * 8u;
    for (; j + 7 < e; j += 8) {
      unsigned o0 = (unsigned)__builtin_amdgcn_readfirstlane(csr[j + 0]) << 9;
      unsigned o1 = (unsigned)__builtin_amdgcn_readfirstlane(csr[j + 1]) << 9;
      unsigned o2 = (unsigned)__builtin_amdgcn_readfirstlane(csr[j + 2]) << 9;
      unsigned o3 = (unsigned)__builtin_amdgcn_readfirstlane(csr[j + 3]) << 9;
      unsigned o4 = (unsigned)__builtin_amdgcn_readfirstlane(csr[j + 4]) << 9;
      unsigned o5 = (unsigned)__builtin_amdgcn_readfirstlane(csr[j + 5]) << 9;
      unsigned o6 = (unsigned)__builtin_amdgcn_readfirstlane(csr[j + 6]) << 9;
      unsigned o7 = (unsigned)__builtin_amdgcn_readfirstlane(csr[j + 7]) << 9;
      float2 v0 = *(const float2*)(hb + (o0 + laneB));
      float2 v1 = *(const float2*)(hb + (o1 + laneB));
      float2 v2 = *(const float2*)(hb + (o2 + laneB));
      float2 v3 = *(const float2*)(hb + (o3 + laneB));
      float2 v4 = *(const float2*)(hb + (o4 + laneB));
      float2 v5 = *(const float2*)(hb + (o5 + laneB));
      float2 v6 = *(const float2*)(hb + (o6 + laneB));
      float2 v7 = *(const float2*)(hb + (o7 + laneB));
      a0 += v0.x; a1 += v0.y;
      b0 += v1.x; b1 += v1.y;
      c0 += v2.x; c1 += v2.y;
      d0 += v3.x; d1 += v3.y;
      g0 += v4.x; g1 += v4.y;
      a0 += v5.x; a1 += v5.y;
      b0 += v6.x; b1 += v6.y;
      c0 += v7.x; c1 += v7.y;
    }
    for (; j < e; ++j) {
      unsigned o = (unsigned)__builtin_amdgcn_readfirstlane(csr[j]) << 9;
      float2 v = *(const float2*)(hb + (o + laneB));
      a0 += v.x; a1 += v.y;
    }
  } else {
    unsigned laneB = (unsigned)lane * 4u;
    for (; j + 7 < e; j += 8) {
      unsigned o0 = (unsigned)__builtin_amdgcn_readfirstlane(csr[j + 0]) << 8;
      unsigned o1 = (unsigned)__builtin_amdgcn_readfirstlane(csr[j + 1]) << 8;
      unsigned o2 = (unsigned)__builtin_amdgcn_readfirstlane(csr[j + 2]) << 8;
      unsigned o3 = (unsigned)__builtin_amdgcn_readfirstlane(csr[j + 3]) << 8;
      unsigned o4 = (unsigned)__builtin_amdgcn_readfirstlane(csr[j + 4]) << 8;
      unsigned o5 = (unsigned)__builtin_amdgcn_readfirstlane(csr[j + 5]) << 8;
      unsigned o6 = (unsigned)__builtin_amdgcn_readfirstlane(csr[j + 6]) << 8;
      unsigned o7 = (unsigned)__builtin_amdgcn_readfirstlane(csr[j + 7]) << 8;
      unsigned int v0 = *(const unsigned int*)(hb + (o0 + laneB));
      unsigned int v1 = *(const unsigned int*)(hb + (o1 + laneB));
      unsigned int v2 = *(const unsigned int*)(hb + (o2 + laneB));
      unsigned int v3 = *(const unsigned int*)(hb + (o3 + laneB));
      unsigned int v4 = *(const unsigned int*)(hb + (o4 + laneB));
      unsigned int v5 = *(const unsigned int*)(hb + (o5 + laneB));
      unsigned int v6 = *(const unsigned int*)(hb + (o6 + laneB));
      unsigned int v7 = *(const unsigned int*)(hb + (o7 + laneB));
      a0 += bfu_lo(v0); a1 += bfu_hi(v0);
      b0 += bfu_lo(v1); b1 += bfu_hi(v1);
      c0 += bfu_lo(v2); c1 += bfu_hi(v2);
      d0 += bfu_lo(v3); d1 += bfu_hi(v3);
      g0 += bfu_lo(v4); g1 += bfu_hi(v4);
      a0 += bfu_lo(v5); a1 += bfu_hi(v5);
      b0 += bfu_lo(v6); b1 += bfu_hi(v6);
      c0 += bfu_lo(v7); c1 += bfu_hi(v7);
    }
    for (; j < e; ++j) {
      unsigned o = (unsigned)__builtin_amdgcn_readfirstlane(csr[j]) << 8;
      unsigned int v = *(const unsigned int*)(hb + (o + laneB));
      a0 += bfu_lo(v); a1 += bfu_hi(v);
    }
  }
  a0 += b0 + c0 + d0 + g0;
  a1 += b1 + c1 + d1 + g1;
  ((unsigned int*)agg)[((unsigned)node << 6) + lane] =
      ((unsigned int)f2bf(a1) << 16) | f2bf(a0);
}

// ---------------- MLP via MFMA bf16 (R3/R7-proven) ----------------

#define MROWS 32

__global__ __launch_bounds__(256) void k_mlp(const unsigned short* __restrict__ agg,
                                             const unsigned short* __restrict__ W1T,
                                             const unsigned short* __restrict__ W2T,
                                             const float* __restrict__ b1,
                                             const float* __restrict__ gamma,
                                             const float* __restrict__ beta,
                                             const float* __restrict__ rmean,
                                             const float* __restrict__ rvar,
                                             const float* __restrict__ b2,
                                             unsigned short* __restrict__ hout) {
  __shared__ __align__(16) char smem[MROWS * 256];   // 8KB
  int t = threadIdx.x;
  int lane = t & 63;
  int wv = t >> 6;
  int r0 = blockIdx.x * MROWS;
  int cl = lane & 15;
  int kg = lane >> 4;

  {
    const uint4* ag4 = (const uint4*)(agg + (size_t)r0 * DIM);
#pragma unroll
    for (int it = 0; it < 2; ++it) {
      int u = t + it * 256;
      int row = u >> 4, un = u & 15;
      uint4 v = make_uint4(0u, 0u, 0u, 0u);
      if (r0 + row < NNODES) v = ag4[u];
      *(uint4*)(smem + row * 256 + ((un * 16) ^ ((row & 7) << 4))) = v;
    }
  }

  bf16x8 b1f[2][4], b2f[2][4];
#pragma unroll
  for (int ct = 0; ct < 2; ++ct) {
    int col = wv * 32 + ct * 16 + cl;
    const char* p1 = (const char*)(W1T + (size_t)col * DIM);
    const char* p2 = (const char*)(W2T + (size_t)col * DIM);
#pragma unroll
    for (int kk = 0; kk < 4; ++kk) {
      b1f[ct][kk] = *(const bf16x8*)(p1 + kk * 64 + kg * 16);
      b2f[ct][kk] = *(const bf16x8*)(p2 + kk * 64 + kg * 16);
    }
  }
  float s1c[2], o1c[2], b2c[2];
#pragma unroll
  for (int ct = 0; ct < 2; ++ct) {
    int col = wv * 32 + ct * 16 + cl;
    float sc = gamma[col] * rsqrtf(rvar[col] + 1e-5f);
    s1c[ct] = sc;
    o1c[ct] = (b1[col] - rmean[col]) * sc + beta[col];
    b2c[ct] = b2[col];
  }
  __syncthreads();

  f32x4 zero = {0.f, 0.f, 0.f, 0.f};
  f32x4 acc[2][2] = {{zero, zero}, {zero, zero}};
#pragma unroll
  for (int kk = 0; kk < 4; ++kk) {
#pragma unroll
    for (int rt = 0; rt < 2; ++rt) {
      int row = rt * 16 + cl;
      int un = kk * 4 + kg;
      bf16x8 a = *(const bf16x8*)(smem + row * 256 + ((un * 16) ^ ((row & 7) << 4)));
      acc[rt][0] = __builtin_amdgcn_mfma_f32_16x16x32_bf16(a, b1f[0][kk], acc[rt][0], 0, 0, 0);
      acc[rt][1] = __builtin_amdgcn_mfma_f32_16x16x32_bf16(a, b1f[1][kk], acc[rt][1], 0, 0, 0);
    }
  }
  __syncthreads();

#pragma unroll
  for (int rt = 0; rt < 2; ++rt)
#pragma unroll
    for (int ct = 0; ct < 2; ++ct) {
      int col = wv * 32 + ct * 16 + cl;
#pragma unroll
      for (int j = 0; j < 4; ++j) {
        int row = rt * 16 + kg * 4 + j;
        float z = fmaxf(acc[rt][ct][j] * s1c[ct] + o1c[ct], 0.f);
        *(unsigned short*)(smem + row * 256 + ((col * 2) ^ ((row & 7) << 4))) = f2bf(z);
      }
    }
  __syncthreads();

  f32x4 acc2[2][2] = {{zero, zero}, {zero, zero}};
#pragma unroll
  for (int kk = 0; kk < 4; ++kk) {
#pragma unroll
    for (int rt = 0; rt < 2; ++rt) {
      int row = rt * 16 + cl;
      int un = kk * 4 + kg;
      bf16x8 a = *(const bf16x8*)(smem + row * 256 + ((un * 16) ^ ((row & 7) << 4)));
      acc2[rt][0] = __builtin_amdgcn_mfma_f32_16x16x32_bf16(a, b2f[0][kk], acc2[rt][0], 0, 0, 0);
      acc2[rt][1] = __builtin_amdgcn_mfma_f32_16x16x32_bf16(a, b2f[1][kk], acc2[rt][1], 0, 0, 0);
    }
  }
  __syncthreads();

#pragma unroll
  for (int rt = 0; rt < 2; ++rt)
#pragma unroll
    for (int ct = 0; ct < 2; ++ct) {
      int col = wv * 32 + ct * 16 + cl;
#pragma unroll
      for (int j = 0; j < 4; ++j) {
        int row = rt * 16 + kg * 4 + j;
        float hv = fmaxf(acc2[rt][ct][j] + b2c[ct], 0.f);
        *(unsigned short*)(smem + row * 256 + ((col * 2) ^ ((row & 7) << 4))) = f2bf(hv);
      }
    }
  __syncthreads();

  {
    uint4* ho4 = (uint4*)(hout + (size_t)r0 * DIM);
#pragma unroll
    for (int it = 0; it < 2; ++it) {
      int u = t + it * 256;
      int row = u >> 4, un = u & 15;
      if (r0 + row < NNODES) {
        uint4 v = *(const uint4*)(smem + row * 256 + ((un * 16) ^ ((row & 7) << 4)));
        ho4[u] = v;
      }
    }
  }
}

// ---------------- mean-pool + final linear ----------------

__device__ inline int lower_bound_i(const int* a, int n, int key) {
  int lo = 0, hi = n;
  while (lo < hi) {
    int m = (lo + hi) >> 1;
    if (a[m] < key) lo = m + 1; else hi = m;
  }
  return lo;
}

__global__ __launch_bounds__(256) void k_pool(const unsigned short* __restrict__ h,
                                              const int* __restrict__ batch,
                                              const float* __restrict__ Wout,
                                              const float* __restrict__ bout,
                                              float* __restrict__ out) {
  int g = blockIdx.x;
  int t = threadIdx.x;
  int cg = t & 31;
  int st = t >> 5;
  int lo = lower_bound_i(batch, NNODES, g);
  int hi = lower_bound_i(batch, NNODES, g + 1);
  const uint2* h2 = (const uint2*)h;
  float a0 = 0.f, a1 = 0.f, a2 = 0.f, a3 = 0.f;
  for (int i = lo + st; i < hi; i += 8) {
    uint2 v = h2[(size_t)i * 32 + cg];
    a0 += bfu_lo(v.x); a1 += bfu_hi(v.x); a2 += bfu_lo(v.y); a3 += bfu_hi(v.y);
  }
  __shared__ float red[8][DIM];
  __shared__ float pooled[DIM];
  red[st][cg * 4 + 0] = a0; red[st][cg * 4 + 1] = a1;
  red[st][cg * 4 + 2] = a2; red[st][cg * 4 + 3] = a3;
  __syncthreads();
  if (t < DIM) {
    float s = 0.f;
#pragma unroll
    for (int k = 0; k < 8; ++k) s += red[k][t];
    float cnt = (hi > lo) ? (float)(hi - lo) : 1.0f;
    pooled[t] = s / cnt;
  }
  __syncthreads();
  if (t < DOUT) {
    float acc = bout[t];
#pragma unroll 8
    for (int k = 0; k < DIM; ++k) acc = fmaf(pooled[k], Wout[k * DOUT + t], acc);
    out[g * DOUT + t] = acc;
  }
}

// ---------------- launch ----------------

extern "C" void kernel_launch(void* const* d_in, const int* in_sizes, int n_in,
                              void* d_out, int out_size, void* d_ws, size_t ws_size,
                              hipStream_t stream) {
  const float* x     = (const float*)d_in[0];
  const int*   ei    = (const int*)d_in[1];
  const int*   batch = (const int*)d_in[2];
  const float* W1    = (const float*)d_in[3];
  const float* b1    = (const float*)d_in[4];
  const float* gamma = (const float*)d_in[5];
  const float* beta  = (const float*)d_in[6];
  const float* rmean = (const float*)d_in[7];
  const float* rvar  = (const float*)d_in[8];
  const float* W2    = (const float*)d_in[9];
  const float* b2    = (const float*)d_in[10];
  const float* eps   = (const float*)d_in[11];
  const float* Wout  = (const float*)d_in[12];
  const float* bout  = (const float*)d_in[13];
  float* out = (float*)d_out;

  const int* src = ei;
  const int* dst = ei + NEDGES;

  char* ws = (char*)d_ws;
  size_t o = 0;
  auto alloc = [&](size_t bytes) -> void* {
    o = (o + 255) & ~(size_t)255;
    void* p = ws + o;
    o += bytes;
    return p;
  };
  // deg8 + bflag contiguous -> single memset
  int* deg8    = (int*)alloc((size_t)NCOPY * NPAD * sizeof(int));
  int* bflag   = (int*)alloc(64 * sizeof(int));          // must follow deg8 (memset span)
  int* bsum    = (int*)alloc(64 * sizeof(int));
  int* cursor8 = (int*)alloc((size_t)NCOPY * NPAD * sizeof(int));
  int* offs    = (int*)alloc((NPAD + 8) * sizeof(int));
  int* csr     = (int*)alloc(NEDGES * sizeof(int));
  unsigned short* agg = (unsigned short*)alloc((size_t)NNODES * DIM * 2);
  unsigned short* hA  = (unsigned short*)alloc((size_t)NNODES * DIM * 2);
  unsigned short* hB  = (unsigned short*)alloc((size_t)NNODES * DIM * 2);
  unsigned short* W1T = (unsigned short*)alloc(3 * DIM * DIM * 2);
  unsigned short* W2T = (unsigned short*)alloc(3 * DIM * DIM * 2);

  // zero deg8 + bflag in one fill (they are adjacent modulo 256B padding; cover both)
  size_t z_span = (size_t)((char*)(bflag + 64) - (char*)deg8);
  hipMemsetAsync(deg8, 0, z_span, stream);

  k_prep<<<EDGE_NB + 6, 256, 0, stream>>>(dst, deg8, W1, W2, W1T, W2T);
  k_scan<<<32, 256, 0, stream>>>(deg8, offs, cursor8, bsum, bflag);
  k_scatter<<<EDGE_NB, 256, 0, stream>>>(src, dst, cursor8, csr);

  // layer 0: gather directly from f32 x
  k_agg<true><<<NNODES / 4, 256, 0, stream>>>(x, offs, csr, eps, 0, agg);
  k_mlp<<<(NNODES + MROWS - 1) / MROWS, 256, 0, stream>>>(
      agg, W1T, W2T, b1, gamma, beta, rmean, rvar, b2, hA);

  // layer 1
  k_agg<false><<<NNODES / 4, 256, 0, stream>>>(hA, offs, csr, eps, 1, agg);
  k_mlp<<<(NNODES + MROWS - 1) / MROWS, 256, 0, stream>>>(
      agg, W1T + DIM * DIM, W2T + DIM * DIM, b1 + DIM, gamma + DIM, beta + DIM,
      rmean + DIM, rvar + DIM, b2 + DIM, hB);

  // layer 2
  k_agg<false><<<NNODES / 4, 256, 0, stream>>>(hB, offs, csr, eps, 2, agg);
  k_mlp<<<(NNODES + MROWS - 1) / MROWS, 256, 0, stream>>>(
      agg, W1T + 2 * DIM * DIM, W2T + 2 * DIM * DIM, b1 + 2 * DIM, gamma + 2 * DIM,
      beta + 2 * DIM, rmean + 2 * DIM, rvar + 2 * DIM, b2 + 2 * DIM, hA);

  k_pool<<<NGRAPHS, 256, 0, stream>>>(hA, batch, Wout, bout, out);
}